// Round 2
// baseline (498.582 us; speedup 1.0000x reference)
//
#include <hip/hip_runtime.h>

#define HID 4096
#define NTOK 4096

typedef float f32x4 __attribute__((ext_vector_type(4)));

// ---- helpers -------------------------------------------------------------

__device__ inline unsigned int pack_fp8x4(float a, float b, float c, float d) {
  // v_cvt_pk_fp8_f32 is RNE on gfx950 (OCP e4m3fn)
  int p = __builtin_amdgcn_cvt_pk_fp8_f32(a, b, 0, false);   // bytes 0,1
  p = __builtin_amdgcn_cvt_pk_fp8_f32(c, d, p, true);        // bytes 2,3
  return (unsigned int)p;
}

__device__ inline void gload16(const void* g, void* l) {
  __builtin_amdgcn_global_load_lds(
      (const __attribute__((address_space(1))) unsigned int*)g,
      (__attribute__((address_space(3))) unsigned int*)l, 16, 0, 0);
}

// ---- kernel 1: y = silu(gate)*up ; q8 = fp8(clip(y/s)) -------------------
// x: [4096][8192] f32 (gate cols 0..4095, up cols 4096..8191)
// q8: [4096][4096] fp8 bytes

__global__ __launch_bounds__(256) void k_silu_quant(
    const float* __restrict__ x, const float* __restrict__ wscale,
    unsigned char* __restrict__ q8) {
  const float s = wscale[0];
  const int idx = blockIdx.x * 256 + threadIdx.x;   // 0 .. 2M-1, 8 elems each
  const int row = idx >> 9;                          // 512 threads per row
  const int col = (idx & 511) * 8;
  const float* gp = x + (size_t)row * (2 * HID) + col;
  f32x4 g0 = *(const f32x4*)gp;
  f32x4 g1 = *(const f32x4*)(gp + 4);
  f32x4 u0 = *(const f32x4*)(gp + HID);
  f32x4 u1 = *(const f32x4*)(gp + HID + 4);
  float q[8];
#pragma unroll
  for (int j = 0; j < 4; ++j) {
    float g = g0[j];
    float sg = 1.0f / (1.0f + expf(-g));   // exact f32 div, matches np
    float v = (g * sg * u0[j]) / s;
    q[j] = fminf(fmaxf(v, -448.0f), 448.0f);
  }
#pragma unroll
  for (int j = 0; j < 4; ++j) {
    float g = g1[j];
    float sg = 1.0f / (1.0f + expf(-g));
    float v = (g * sg * u1[j]) / s;
    q[4 + j] = fminf(fmaxf(v, -448.0f), 448.0f);
  }
  unsigned int lo = pack_fp8x4(q[0], q[1], q[2], q[3]);
  unsigned int hi = pack_fp8x4(q[4], q[5], q[6], q[7]);
  unsigned long long pk = ((unsigned long long)hi << 32) | lo;
  *(unsigned long long*)(q8 + (size_t)idx * 8) = pk;
}

// ---- kernel 2: wT8[n][k] = fp8(w[k][n])  (exact: w is fp8-representable) -

__global__ __launch_bounds__(256) void k_wq_transpose(
    const float* __restrict__ w, unsigned char* __restrict__ wT8) {
  __shared__ float lds[64][65];   // +1 pad: conflict-free col reads
  const int t = threadIdx.x;
  const int bk = (blockIdx.x >> 6) * 64;   // K-tile origin
  const int bn = (blockIdx.x & 63) * 64;   // N-tile origin
#pragma unroll
  for (int it = 0; it < 4; ++it) {
    int f = t + it * 256;        // 0..1023 float4 slots
    int r = f >> 4;              // k row 0..63
    int c = (f & 15) * 4;        // n col
    f32x4 v = *(const f32x4*)(w + (size_t)(bk + r) * HID + bn + c);
    lds[r][c + 0] = v.x; lds[r][c + 1] = v.y;
    lds[r][c + 2] = v.z; lds[r][c + 3] = v.w;
  }
  __syncthreads();
  const int n = t >> 2;            // 0..63 output row (N dim)
  const int ch = (t & 3) * 16;     // k chunk of 16
  unsigned int pk[4];
#pragma unroll
  for (int qq = 0; qq < 4; ++qq) {
    float a = lds[ch + 4 * qq + 0][n];
    float b = lds[ch + 4 * qq + 1][n];
    float c2 = lds[ch + 4 * qq + 2][n];
    float d = lds[ch + 4 * qq + 3][n];
    pk[qq] = pack_fp8x4(a, b, c2, d);
  }
  uint4 vv; vv.x = pk[0]; vv.y = pk[1]; vv.z = pk[2]; vv.w = pk[3];
  *(uint4*)(wT8 + (size_t)(bn + n) * HID + bk + ch) = vv;
}

// ---- kernel 3: out[m][n] = s^2 * sum_k q8[m][k] * wT8[n][k] --------------
// m97/m145-structure: 128x128 tile, BK=64, 4 waves, 16x16x32 fp8 MFMA

#define BM 128
#define BN 128
#define BK 64

__global__ __launch_bounds__(256) void k_gemm_fp8(
    const unsigned char* __restrict__ A8, const unsigned char* __restrict__ B8,
    const float* __restrict__ wscale, float* __restrict__ out) {
  __shared__ unsigned char sA[BM * BK];   // 8 KB, [128 rows][64 k-bytes]
  __shared__ unsigned char sB[BN * BK];   // 8 KB
  const int t = threadIdx.x;
  const int lane = t & 63;
  const int wv = t >> 6;                  // wave 0..3
  const int wr = wv >> 1, wc = wv & 1;    // 2x2 waves of 64x64
  const int bid = blockIdx.x;
  const int brow = (bid >> 5) * BM;       // 32x32 blocks
  const int bcol = (bid & 31) * BN;

  f32x4 acc[4][4] = {};

  // staging: thread t loads 16B at row t/4, bytecol (t%4)*16 (per 64-row half)
  const int roff = t >> 2;
  const int coff = (t & 3) * 16;
  const unsigned char* gA = A8 + (size_t)(brow + roff) * HID + coff;
  const unsigned char* gB = B8 + (size_t)(bcol + roff) * HID + coff;
  unsigned char* lA = &sA[t * 16];
  unsigned char* lB = &sB[t * 16];
  const size_t half = (size_t)64 * HID;

  for (int kt = 0; kt < HID; kt += BK) {
    gload16(gA + kt, lA);
    gload16(gA + kt + half, lA + 4096);
    gload16(gB + kt, lB);
    gload16(gB + kt + half, lB + 4096);
    __syncthreads();   // drain staging (vmcnt 0) + barrier
#pragma unroll
    for (int ks = 0; ks < 2; ++ks) {
      long long af[4], bf[4];
#pragma unroll
      for (int i = 0; i < 4; ++i) {
        int ra = 64 * wr + 16 * i + (lane & 15);
        af[i] = *(const long long*)&sA[ra * BK + ks * 32 + (lane >> 4) * 8];
        int rb = 64 * wc + 16 * i + (lane & 15);
        bf[i] = *(const long long*)&sB[rb * BK + ks * 32 + (lane >> 4) * 8];
      }
#pragma unroll
      for (int i = 0; i < 4; ++i)
#pragma unroll
        for (int j = 0; j < 4; ++j)
          acc[i][j] = __builtin_amdgcn_mfma_f32_16x16x32_fp8_fp8(
              af[i], bf[j], acc[i][j], 0, 0, 0);
    }
    __syncthreads();   // all waves done reading before next overwrite
  }

  const float s = wscale[0];
  const float s2 = s * s;
#pragma unroll
  for (int i = 0; i < 4; ++i) {
    int row0 = brow + 64 * wr + 16 * i + ((lane >> 4) * 4);
#pragma unroll
    for (int j = 0; j < 4; ++j) {
      int col = bcol + 64 * wc + 16 * j + (lane & 15);
#pragma unroll
      for (int r = 0; r < 4; ++r)
        out[(size_t)(row0 + r) * HID + col] = acc[i][j][r] * s2;
    }
  }
}

// ---- launch --------------------------------------------------------------

extern "C" void kernel_launch(void* const* d_in, const int* in_sizes, int n_in,
                              void* d_out, int out_size, void* d_ws, size_t ws_size,
                              hipStream_t stream) {
  const float* x = (const float*)d_in[0];        // [4096][8192]
  const float* w = (const float*)d_in[1];        // [4096][4096]
  const float* wscale = (const float*)d_in[2];   // [1]
  float* out = (float*)d_out;                    // [4096][4096]

  unsigned char* q8 = (unsigned char*)d_ws;                    // 16 MB
  unsigned char* wT8 = q8 + (size_t)NTOK * HID;                // 16 MB

  // 1) fused silu*up + fp8 quant: 2M threads x 8 elems
  k_silu_quant<<<(NTOK * HID / 8) / 256, 256, 0, stream>>>(x, wscale, q8);
  // 2) transpose + quant w: 64x64 tiles
  k_wq_transpose<<<(HID / 64) * (HID / 64), 256, 0, stream>>>(w, wT8);
  // 3) fp8 GEMM
  k_gemm_fp8<<<(NTOK / BM) * (HID / BN), 256, 0, stream>>>(q8, wT8, wscale, out);
}

// Round 3
// 358.122 us; speedup vs baseline: 1.3922x; 1.3922x over previous
//
#include <hip/hip_runtime.h>

#define HID 4096
#define NTOK 4096

typedef float f32x4 __attribute__((ext_vector_type(4)));

// ---- helpers -------------------------------------------------------------

__device__ inline unsigned int pack_fp8x4(float a, float b, float c, float d) {
  // v_cvt_pk_fp8_f32 is RNE saturating on gfx950 (OCP e4m3fn)
  int p = __builtin_amdgcn_cvt_pk_fp8_f32(a, b, 0, false);   // bytes 0,1
  p = __builtin_amdgcn_cvt_pk_fp8_f32(c, d, p, true);        // bytes 2,3
  return (unsigned int)p;
}

__device__ inline void gload16(const void* g, void* l) {
  __builtin_amdgcn_global_load_lds(
      (const __attribute__((address_space(1))) unsigned int*)g,
      (__attribute__((address_space(3))) unsigned int*)l, 16, 0, 0);
}

// ---- fused prep: silu-quant (blocks 0..8191) + w transpose (blocks 8192+) -

#define NB_SILU 8192

__global__ __launch_bounds__(256) void k_prep(
    const float* __restrict__ x, const float* __restrict__ w,
    const float* __restrict__ wscale, unsigned char* __restrict__ q8,
    unsigned char* __restrict__ wT8) {
  const int t = threadIdx.x;
  if (blockIdx.x < NB_SILU) {
    // ---- y = silu(gate)*up ; q8 = fp8(clip(y/s)) ----
    const float s = wscale[0];
    const int idx = blockIdx.x * 256 + t;           // 8 elems each
    const int row = idx >> 9;                        // 512 threads per row
    const int col = (idx & 511) * 8;
    const float* gp = x + (size_t)row * (2 * HID) + col;
    f32x4 g0 = *(const f32x4*)gp;
    f32x4 g1 = *(const f32x4*)(gp + 4);
    f32x4 u0 = *(const f32x4*)(gp + HID);
    f32x4 u1 = *(const f32x4*)(gp + HID + 4);
    float q[8];
#pragma unroll
    for (int j = 0; j < 4; ++j) {
      float g = g0[j];
      float sg = 1.0f / (1.0f + expf(-g));
      float v = (g * sg * u0[j]) / s;
      q[j] = fminf(fmaxf(v, -448.0f), 448.0f);
    }
#pragma unroll
    for (int j = 0; j < 4; ++j) {
      float g = g1[j];
      float sg = 1.0f / (1.0f + expf(-g));
      float v = (g * sg * u1[j]) / s;
      q[4 + j] = fminf(fmaxf(v, -448.0f), 448.0f);
    }
    unsigned int lo = pack_fp8x4(q[0], q[1], q[2], q[3]);
    unsigned int hi = pack_fp8x4(q[4], q[5], q[6], q[7]);
    unsigned long long pk = ((unsigned long long)hi << 32) | lo;
    *(unsigned long long*)(q8 + (size_t)idx * 8) = pk;
  } else {
    // ---- wT8[n][k] = fp8(w[k][n]) (exact: w is fp8-representable) ----
    __shared__ float lds[64][65];   // +1 pad: conflict-free col reads
    const int bid = blockIdx.x - NB_SILU;
    const int bk = (bid >> 6) * 64;   // K-tile origin
    const int bn = (bid & 63) * 64;   // N-tile origin
#pragma unroll
    for (int it = 0; it < 4; ++it) {
      int f = t + it * 256;        // 0..1023 float4 slots
      int r = f >> 4;              // k row 0..63
      int c = (f & 15) * 4;        // n col
      f32x4 v = *(const f32x4*)(w + (size_t)(bk + r) * HID + bn + c);
      lds[r][c + 0] = v.x; lds[r][c + 1] = v.y;
      lds[r][c + 2] = v.z; lds[r][c + 3] = v.w;
    }
    __syncthreads();
    const int n = t >> 2;            // 0..63 output row (N dim)
    const int ch = (t & 3) * 16;     // k chunk of 16
    unsigned int pk[4];
#pragma unroll
    for (int qq = 0; qq < 4; ++qq) {
      float a = lds[ch + 4 * qq + 0][n];
      float b = lds[ch + 4 * qq + 1][n];
      float c2 = lds[ch + 4 * qq + 2][n];
      float d = lds[ch + 4 * qq + 3][n];
      pk[qq] = pack_fp8x4(a, b, c2, d);
    }
    uint4 vv; vv.x = pk[0]; vv.y = pk[1]; vv.z = pk[2]; vv.w = pk[3];
    *(uint4*)(wT8 + (size_t)(bn + n) * HID + bk + ch) = vv;
  }
}

// ---- GEMM: out[m][n] = s^2 * sum_k q8[m][k] * wT8[n][k] ------------------
// 128x128 tile, BK=128 fp8 (rows of 128B), 4 waves, 16x16x32 fp8 MFMA.
// LDS bank-conflict fix: 16B-chunk XOR swizzle chunk' = chunk ^ (row&7),
// applied BOTH sides (pre-swizzled global_load_lds source + swizzled
// ds_read addr). LDS dest stays linear (rule #21).

#define BM 128
#define BN 128
#define BK 128

__global__ __launch_bounds__(256) void k_gemm_fp8(
    const unsigned char* __restrict__ A8, const unsigned char* __restrict__ B8,
    const float* __restrict__ wscale, float* __restrict__ out) {
  __shared__ unsigned char sA[BM * BK];   // 16 KB, rows of 128B (8 chunks)
  __shared__ unsigned char sB[BN * BK];   // 16 KB
  const int t = threadIdx.x;
  const int lane = t & 63;
  const int hi = lane >> 4;               // k-group within fragment
  const int wv = t >> 6;                  // wave 0..3
  const int wr = wv >> 1, wc = wv & 1;    // 2x2 waves of 64x64
  const int bid = blockIdx.x;
  const int brow = (bid >> 5) * BM;       // 32 row-blocks x 32 col-blocks
  const int bcol = (bid & 31) * BN;

  f32x4 acc[4][4] = {};

  // --- staging (pre-swizzled source) ---
  // thread t stages LDS chunks q = t + 256*j (bytes t*16 + 4096*j), j=0..3.
  // row(q) = q>>3 = (t>>3) + 32*j ; c' = q&7 = t&7 ; source chunk
  // c = c' ^ (row&7) = (t&7) ^ ((t>>3)&7)  (same for all j).
  const int csrc16 = (((t & 7) ^ ((t >> 3) & 7)) * 16);
  const int r0 = t >> 3;
  const unsigned char* gA = A8 + (size_t)(brow + r0) * HID + csrc16;
  const unsigned char* gB = B8 + (size_t)(bcol + r0) * HID + csrc16;
  unsigned char* lA = &sA[t * 16];
  unsigned char* lB = &sB[t * 16];
  const size_t rowstep = (size_t)32 * HID;   // j advances 32 rows

  // --- fragment read offsets (loop-invariant) ---
  // frag(row, ks): LDS byte = row*128 + ((2ks+(hi>>1)) ^ (row&7))*16 + (hi&1)*8
  // row = 64*w? + 16*i + (lane&15)  =>  row&7 = lane&7
  const int arow = 64 * wr + (lane & 15);
  const int brw = 64 * wc + (lane & 15);
  int ks_off[4];
#pragma unroll
  for (int ks = 0; ks < 4; ++ks)
    ks_off[ks] = (((2 * ks + (hi >> 1)) ^ (lane & 7)) * 16) + (hi & 1) * 8;

  for (int kt = 0; kt < HID; kt += BK) {
#pragma unroll
    for (int j = 0; j < 4; ++j) {
      gload16(gA + kt + j * rowstep, lA + j * 4096);
      gload16(gB + kt + j * rowstep, lB + j * 4096);
    }
    __syncthreads();   // drain staging + barrier
#pragma unroll
    for (int ks = 0; ks < 4; ++ks) {
      long long af[4], bf[4];
#pragma unroll
      for (int i = 0; i < 4; ++i) {
        af[i] = *(const long long*)&sA[(arow + 16 * i) * BK + ks_off[ks]];
        bf[i] = *(const long long*)&sB[(brw + 16 * i) * BK + ks_off[ks]];
      }
#pragma unroll
      for (int i = 0; i < 4; ++i)
#pragma unroll
        for (int j = 0; j < 4; ++j)
          acc[i][j] = __builtin_amdgcn_mfma_f32_16x16x32_fp8_fp8(
              af[i], bf[j], acc[i][j], 0, 0, 0);
    }
    __syncthreads();   // all waves done reading before next overwrite
  }

  const float s = wscale[0];
  const float s2 = s * s;
#pragma unroll
  for (int i = 0; i < 4; ++i) {
    int row0 = brow + 64 * wr + 16 * i + ((lane >> 4) * 4);
#pragma unroll
    for (int j = 0; j < 4; ++j) {
      int col = bcol + 64 * wc + 16 * j + (lane & 15);
#pragma unroll
      for (int r = 0; r < 4; ++r)
        out[(size_t)(row0 + r) * HID + col] = acc[i][j][r] * s2;
    }
  }
}

// ---- launch --------------------------------------------------------------

extern "C" void kernel_launch(void* const* d_in, const int* in_sizes, int n_in,
                              void* d_out, int out_size, void* d_ws, size_t ws_size,
                              hipStream_t stream) {
  const float* x = (const float*)d_in[0];        // [4096][8192]
  const float* w = (const float*)d_in[1];        // [4096][4096]
  const float* wscale = (const float*)d_in[2];   // [1]
  float* out = (float*)d_out;                    // [4096][4096]

  unsigned char* q8 = (unsigned char*)d_ws;                    // 16 MB
  unsigned char* wT8 = q8 + (size_t)NTOK * HID;                // 16 MB

  // fused silu-quant (8192 blocks) + w transpose-quant (4096 blocks)
  k_prep<<<NB_SILU + (HID / 64) * (HID / 64), 256, 0, stream>>>(x, w, wscale,
                                                                q8, wT8);
  // fp8 GEMM
  k_gemm_fp8<<<(NTOK / BM) * (HID / BN), 256, 0, stream>>>(q8, wT8, wscale, out);
}